// Round 4
// baseline (890.443 us; speedup 1.0000x reference)
//
#include <hip/hip_runtime.h>
#include <hip/hip_bf16.h>
#include <math.h>

#define MBLK    128
#define H0_OFF  131072                // act: 128 rows x 1024B (512 bf16 cols), XOR-swizzled
#define LDSB    (H0_OFF + 128*64)     // +h0: 128 rows x 64B = 139264 total

// packed bf16 weight offsets (ushort elements) inside d_ws
#define OFF_W1  0
#define OFF_W2  16384                    // 512*32
#define OFF_WS1 (16384+262144)           // 278528
#define OFF_WS2 (278528+278528)          // 557056
#define OFF_WO  (557056+262144)          // 819200
#define NPACK   (819200+1024)            // 820224

typedef __attribute__((ext_vector_type(8))) short bf16x8;
typedef __attribute__((ext_vector_type(4))) float f32x4;

struct ResArr { int r[10]; };

__device__ __forceinline__ unsigned short f2bf(float f) {
    unsigned u = __float_as_uint(f);
    u += 0x7FFFu + ((u >> 16) & 1u);       // RNE
    return (unsigned short)(u >> 16);
}
__device__ __forceinline__ float bf2f(unsigned short h) {
    return __uint_as_float(((unsigned)h) << 16);
}
__device__ __forceinline__ unsigned cvt_pk_bf16(float a, float b) {
    unsigned r;
    asm("v_cvt_pk_bf16_f32 %0, %1, %2" : "=v"(r) : "v"(a), "v"(b));
    return r;                               // low16=bf16(a), high16=bf16(b)
}

__global__ void pack_weights(const float* __restrict__ w1, const float* __restrict__ w2,
                             const float* __restrict__ ws1, const float* __restrict__ ws2,
                             const float* __restrict__ wo, unsigned short* __restrict__ out)
{
    int i = blockIdx.x * 256 + threadIdx.x;
    if (i >= NPACK) return;
    float v;
    if (i < OFF_W2)       { int n = i >> 5,  k = i & 31;  v = (k < 22)  ? w1[n*22 + k]  : 0.f; }
    else if (i < OFF_WS1) { int j = i - OFF_W2;  int n = j >> 9, k = j & 511; v = w2[n*512 + k]; }
    else if (i < OFF_WS2) { int j = i - OFF_WS1; int n = j / 544, k = j - n*544; v = (k < 534) ? ws1[n*534 + k] : 0.f; }
    else if (i < OFF_WO)  { int j = i - OFF_WS2; int n = j >> 9, k = j & 511; v = ws2[n*512 + k]; }
    else                  { int j = i - OFF_WO;  v = wo[j]; }
    out[i] = f2bf(v);
}

// One MLP layer, in-place on the 128x512 act buffer.
// acc = mfma(W_frag, act_frag)  => D[n][m]: col(lane&15)=act row, row(lk*4+j)=n
template<int KSTEPS, bool TAIL, int KPAD, bool PREBAR>
__device__ __forceinline__ void mlp_layer(char* sm, const unsigned short* __restrict__ Wp,
                                          const float* __restrict__ bias,
                                          int wid, int lane)
{
    const int n0 = wid * 64;
    const int lm = lane & 15;
    const int lk = lane >> 4;               // 0..3
    const int xm = (lm & 7) << 4;
    constexpr int NC = KSTEPS + (TAIL ? 1 : 0);

    f32x4 acc[8][4];
    #pragma unroll
    for (int i = 0; i < 8; ++i)
        #pragma unroll
        for (int j = 0; j < 4; ++j) { f32x4 z = {0.f,0.f,0.f,0.f}; acc[i][j] = z; }

    const unsigned short* wb = Wp + (unsigned)(n0 + lm) * KPAD + lk * 8;

    bf16x8 b[4];
    #pragma unroll
    for (int nf = 0; nf < 4; ++nf) b[nf] = *(const bf16x8*)(wb + nf*16*KPAD);

    #pragma unroll
    for (int c = 0; c < NC; ++c) {
        bf16x8 bn[4];
        if (c + 1 < NC) {                    // prefetch next B chunk
            #pragma unroll
            for (int nf = 0; nf < 4; ++nf)
                bn[nf] = *(const bf16x8*)(wb + nf*16*KPAD + (c+1)*32);
        }
        bf16x8 a[8];
        #pragma unroll
        for (int mf = 0; mf < 8; ++mf) {
            int row = mf*16 + lm;
            const char* ap = (c < KSTEPS)
                ? sm + ((((row << 10) + c*64 + lk*16)) ^ xm)
                : sm + H0_OFF + ((((row << 6) + lk*16)) ^ xm);
            a[mf] = *(const bf16x8*)ap;
        }
        #pragma unroll
        for (int mf = 0; mf < 8; ++mf)
            #pragma unroll
            for (int nf = 0; nf < 4; ++nf)
                acc[mf][nf] = __builtin_amdgcn_mfma_f32_16x16x32_bf16(b[nf], a[mf], acc[mf][nf], 0, 0, 0);
        if (c + 1 < NC) {
            #pragma unroll
            for (int nf = 0; nf < 4; ++nf) b[nf] = bn[nf];
        }
    }

    if (PREBAR) __syncthreads();    // everyone done reading act before overwrite

    #pragma unroll
    for (int nf = 0; nf < 4; ++nf) {
        const float4 bv = *(const float4*)(bias + n0 + nf*16 + lk*4);
        const int colb = (n0 + nf*16 + lk*4) * 2;
        #pragma unroll
        for (int mf = 0; mf < 8; ++mf) {
            float s0 = __sinf(acc[mf][nf][0] + bv.x);
            float s1 = __sinf(acc[mf][nf][1] + bv.y);
            float s2 = __sinf(acc[mf][nf][2] + bv.z);
            float s3 = __sinf(acc[mf][nf][3] + bv.w);
            uint2 pk;
            pk.x = cvt_pk_bf16(s0, s1);
            pk.y = cvt_pk_bf16(s2, s3);
            int row = mf*16 + lm;
            *(uint2*)(sm + (((row << 10) + colb) ^ ((row & 7) << 4))) = pk;
        }
    }
    __syncthreads();
}

__global__ __launch_bounds__(512, 2) void siren_fused(
    const float* __restrict__ coords, const float* __restrict__ table,
    const float* __restrict__ b1, const float* __restrict__ b2,
    const float* __restrict__ bs1, const float* __restrict__ bs2,
    const float* __restrict__ bo,
    const unsigned short* __restrict__ Wp,
    float* __restrict__ outp,
    ResArr res)
{
    extern __shared__ char sm[];
    const int tid = threadIdx.x;
    const int pbase = blockIdx.x * MBLK;

    // ---------------- hash encoding -> h0 block (64B rows, swizzled) ----------------
    {
        int p  = tid & 127;
        int lg = tid >> 7;                 // 0..3; handles levels lg, lg+4, lg+8
        float2 cc = ((const float2*)coords)[pbase + p];
        #pragma unroll
        for (int li = 0; li < 3; ++li) {
            int l = lg + 4 * li;
            if (l < 10) {
                float R  = (float)res.r[l];
                float fx = cc.x * R, fy = cc.y * R;
                float x0 = floorf(fx), y0 = floorf(fy);
                float wx = fx - x0,  wy = fy - y0;
                unsigned xi = (unsigned)x0, yi = (unsigned)y0;
                unsigned yp  = yi * 2654435761u;
                unsigned yp1 = (yi + 1u) * 2654435761u;
                unsigned h00 = (xi        ^ yp ) & 4095u;
                unsigned h10 = ((xi + 1u) ^ yp ) & 4095u;
                unsigned h01 = (xi        ^ yp1) & 4095u;
                unsigned h11 = ((xi + 1u) ^ yp1) & 4095u;
                const float2* tl = (const float2*)(table + l * 8192);
                float2 f00 = tl[h00], f10 = tl[h10], f01 = tl[h01], f11 = tl[h11];
                float a0 = f00.x + (f10.x - f00.x) * wx;
                float a1 = f01.x + (f11.x - f01.x) * wx;
                float g0 = a0 + (a1 - a0) * wy;
                float c0 = f00.y + (f10.y - f00.y) * wx;
                float c1 = f01.y + (f11.y - f01.y) * wx;
                float g1 = c0 + (c1 - c0) * wy;
                unsigned pk = (unsigned)f2bf(g0) | ((unsigned)f2bf(g1) << 16);
                *(unsigned*)(sm + H0_OFF + (((p << 6) + 4*l) ^ ((p & 7) << 4))) = pk;
            }
        }
        if (lg == 2) {   // coords -> cols 20,21 (byte 40)
            unsigned pk = (unsigned)f2bf(cc.x) | ((unsigned)f2bf(cc.y) << 16);
            *(unsigned*)(sm + H0_OFF + (((p << 6) + 40) ^ ((p & 7) << 4))) = pk;
        }
        if (lg == 3) {   // zero pad cols 22..31 (bytes 44..63)
            #pragma unroll
            for (int bb = 44; bb < 64; bb += 4)
                *(unsigned*)(sm + H0_OFF + (((p << 6) + bb) ^ ((p & 7) << 4))) = 0u;
        }
    }
    __syncthreads();

    const int wid  = tid >> 6;
    const int lane = tid & 63;

    mlp_layer<0,  true,  32,  false>(sm, Wp + OFF_W1,  b1,  wid, lane);  // h0 -> act
    mlp_layer<16, false, 512, true >(sm, Wp + OFF_W2,  b2,  wid, lane);  // act -> act
    mlp_layer<16, true,  544, true >(sm, Wp + OFF_WS1, bs1, wid, lane);  // [act|h0] -> act
    mlp_layer<16, false, 512, true >(sm, Wp + OFF_WS2, bs2, wid, lane);  // act -> act

    // ---------------- output layer: 512 -> 2, sin, f32 out ----------------
    {
        int p = tid >> 2, g = tid & 3;     // p: 0..127, g: k-quarter
        const unsigned short* wo0 = Wp + OFF_WO + g * 128;
        const unsigned short* wo1 = wo0 + 512;
        int xm = (p & 7) << 4;
        float s0 = 0.f, s1 = 0.f;
        #pragma unroll
        for (int kk = 0; kk < 16; ++kk) {
            int off = ((p << 10) + g*256 + kk*16) ^ xm;
            bf16x8 av  = *(const bf16x8*)(sm + off);
            bf16x8 w0  = *(const bf16x8*)(wo0 + kk * 8);
            bf16x8 w1v = *(const bf16x8*)(wo1 + kk * 8);
            #pragma unroll
            for (int j = 0; j < 8; ++j) {
                float a = bf2f((unsigned short)av[j]);
                s0 += a * bf2f((unsigned short)w0[j]);
                s1 += a * bf2f((unsigned short)w1v[j]);
            }
        }
        #pragma unroll
        for (int m = 1; m < 4; m <<= 1) {
            s0 += __shfl_xor(s0, m, 64);
            s1 += __shfl_xor(s1, m, 64);
        }
        if (g == 0) {
            float2 o;
            o.x = __sinf(s0 + bo[0]);
            o.y = __sinf(s1 + bo[1]);
            ((float2*)outp)[pbase + p] = o;
        }
    }
}

extern "C" void kernel_launch(void* const* d_in, const int* in_sizes, int n_in,
                              void* d_out, int out_size, void* d_ws, size_t ws_size,
                              hipStream_t stream)
{
    const float* coords = (const float*)d_in[0];
    const float* table  = (const float*)d_in[1];
    const float* w1  = (const float*)d_in[2];
    const float* b1  = (const float*)d_in[3];
    const float* w2  = (const float*)d_in[4];
    const float* b2  = (const float*)d_in[5];
    const float* ws1 = (const float*)d_in[6];
    const float* bs1 = (const float*)d_in[7];
    const float* ws2 = (const float*)d_in[8];
    const float* bs2 = (const float*)d_in[9];
    const float* wo  = (const float*)d_in[10];
    const float* bo  = (const float*)d_in[11];

    unsigned short* Wp = (unsigned short*)d_ws;
    float* outp = (float*)d_out;

    // RES computed with the exact double-precision op sequence of the reference
    ResArr res;
    double bb = exp((log(320.0) - log(16.0)) / 9.0);
    for (int l = 0; l < 10; ++l) res.r[l] = (int)floor(16.0 * pow(bb, (double)l));

    (void)hipFuncSetAttribute((const void*)siren_fused,
                              hipFuncAttributeMaxDynamicSharedMemorySize, LDSB);

    int N = in_sizes[0] / 2;      // 262144

    pack_weights<<<(NPACK + 255) / 256, 256, 0, stream>>>(w1, w2, ws1, ws2, wo, Wp);
    siren_fused<<<N / MBLK, 512, LDSB, stream>>>(coords, table, b1, b2, bs1, bs2, bo,
                                                 Wp, outp, res);
}

// Round 6
// 654.487 us; speedup vs baseline: 1.3605x; 1.3605x over previous
//
#include <hip/hip_runtime.h>
#include <hip/hip_bf16.h>
#include <math.h>

#define MBLK    64
#define H0_OFF  65536                 // act: 64 rows x 1024B (512 bf16), XOR-swizzled
#define LDSB    (H0_OFF + 64*64)      // +h0: 64 rows x 64B -> 69632 total (2 blocks/CU)

// packed bf16 weight offsets (ushort elements) inside d_ws
// layout per layer: [nb(8)][chunk(KC)][nf(4)][lane(64)][j(8)]  (coalesced per-wave loads)
#define OFF_W1  0
#define OFF_W2  16384                    // 8*1*4*512
#define OFF_WS1 (16384+262144)           // 278528
#define OFF_WS2 (278528+278528)          // 557056
#define OFF_WO  (557056+262144)          // 819200 (wo row-major, 1024)
#define NPACK   (819200+1024)            // 820224

typedef __attribute__((ext_vector_type(8))) short bf16x8;
typedef __attribute__((ext_vector_type(4))) float f32x4;

struct ResArr { int r[10]; };

__device__ __forceinline__ unsigned short f2bf(float f) {
    unsigned u = __float_as_uint(f);
    u += 0x7FFFu + ((u >> 16) & 1u);       // RNE — matches numpy; do NOT use v_cvt_pk_bf16_f32
    return (unsigned short)(u >> 16);
}
__device__ __forceinline__ float bf2f(unsigned short h) {
    return __uint_as_float(((unsigned)h) << 16);
}

__global__ void pack_weights(const float* __restrict__ w1, const float* __restrict__ w2,
                             const float* __restrict__ ws1, const float* __restrict__ ws2,
                             const float* __restrict__ wo, unsigned short* __restrict__ out)
{
    int i = blockIdx.x * 256 + threadIdx.x;
    if (i >= NPACK) return;
    float v;
    if (i < OFF_WO) {
        int il, KC, K_src, K_valid;
        const float* src;
        if (i < OFF_W2)       { il = i;           KC = 1;  K_src = 22;  K_valid = 22;  src = w1;  }
        else if (i < OFF_WS1) { il = i - OFF_W2;  KC = 16; K_src = 512; K_valid = 512; src = w2;  }
        else if (i < OFF_WS2) { il = i - OFF_WS1; KC = 17; K_src = 534; K_valid = 534; src = ws1; }
        else                  { il = i - OFF_WS2; KC = 16; K_src = 512; K_valid = 512; src = ws2; }
        int blk  = il >> 9, idx = il & 511;
        int lane = idx >> 3, j = idx & 7;
        int nf   = blk & 3;
        int rest = blk >> 2;
        int c    = rest % KC;
        int nb   = rest / KC;
        int n = nb * 64 + nf * 16 + (lane & 15);
        int k = c * 32 + (lane >> 4) * 8 + j;
        v = (k < K_valid) ? src[n * K_src + k] : 0.f;
    } else {
        v = wo[i - OFF_WO];
    }
    out[i] = f2bf(v);
}

// One MLP layer, in-place on the 64x512 act buffer.
// acc = mfma(act_frag, W_frag) => D: row=(lane>>4)*4+j -> act row offset, col=lane&15 -> n
template<int KSTEPS, bool TAIL, bool PREBAR>
__device__ __forceinline__ void mlp_layer(char* sm, const unsigned short* __restrict__ Wl,
                                          const float* __restrict__ bias,
                                          int wid, int lane)
{
    constexpr int NC = KSTEPS + (TAIL ? 1 : 0);
    const int n0 = wid * 64;
    const int lm = lane & 15;
    const int lk = lane >> 4;               // 0..3
    const int xm = (lm & 7) << 4;

    const unsigned short* wnb = Wl + (unsigned)(wid * NC) * 2048 + (lane << 3);

    float bv[4];
    #pragma unroll
    for (int nf = 0; nf < 4; ++nf) bv[nf] = bias[n0 + nf*16 + lm];

    f32x4 acc[4][4];
    #pragma unroll
    for (int i = 0; i < 4; ++i)
        #pragma unroll
        for (int j = 0; j < 4; ++j) { f32x4 z = {0.f,0.f,0.f,0.f}; acc[i][j] = z; }

    #pragma unroll 2
    for (int ks = 0; ks < KSTEPS; ++ks) {
        bf16x8 a[4], b[4];
        #pragma unroll
        for (int nf = 0; nf < 4; ++nf)
            b[nf] = *(const bf16x8*)(wnb + ((ks*4 + nf) << 9));
        #pragma unroll
        for (int mf = 0; mf < 4; ++mf)
            a[mf] = *(const bf16x8*)(sm + ((((mf*16 + lm) << 10) + ks*64 + lk*16) ^ xm));
        #pragma unroll
        for (int mf = 0; mf < 4; ++mf)
            #pragma unroll
            for (int nf = 0; nf < 4; ++nf)
                acc[mf][nf] = __builtin_amdgcn_mfma_f32_16x16x32_bf16(a[mf], b[nf], acc[mf][nf], 0, 0, 0);
    }
    if (TAIL) {   // K-tail of 32 from the h0 block (64B rows, swizzled)
        bf16x8 a[4], b[4];
        #pragma unroll
        for (int nf = 0; nf < 4; ++nf)
            b[nf] = *(const bf16x8*)(wnb + ((KSTEPS*4 + nf) << 9));
        #pragma unroll
        for (int mf = 0; mf < 4; ++mf)
            a[mf] = *(const bf16x8*)(sm + H0_OFF + ((((mf*16 + lm) << 6) + lk*16) ^ xm));
        #pragma unroll
        for (int mf = 0; mf < 4; ++mf)
            #pragma unroll
            for (int nf = 0; nf < 4; ++nf)
                acc[mf][nf] = __builtin_amdgcn_mfma_f32_16x16x32_bf16(a[mf], b[nf], acc[mf][nf], 0, 0, 0);
    }

    if (PREBAR) __syncthreads();    // all waves done reading act before overwrite

    // epilogue: bias + sin -> bf16 (manual RNE) -> act in-place
    #pragma unroll
    for (int nf = 0; nf < 4; ++nf) {
        const int colb = (n0 + nf*16 + lm) * 2;
        #pragma unroll
        for (int mf = 0; mf < 4; ++mf) {
            #pragma unroll
            for (int j = 0; j < 4; ++j) {
                int row = mf*16 + lk*4 + j;
                unsigned short h = f2bf(__sinf(acc[mf][nf][j] + bv[nf]));
                *(unsigned short*)(sm + (((row << 10) + colb) ^ ((row & 7) << 4))) = h;
            }
        }
    }
    __syncthreads();
}

__global__ __launch_bounds__(512, 4) void siren_fused(
    const float* __restrict__ coords, const float* __restrict__ table,
    const float* __restrict__ b1, const float* __restrict__ b2,
    const float* __restrict__ bs1, const float* __restrict__ bs2,
    const float* __restrict__ bo,
    const unsigned short* __restrict__ Wp,
    float* __restrict__ outp,
    ResArr res)
{
    extern __shared__ char sm[];
    const int tid = threadIdx.x;
    const int pbase = blockIdx.x * MBLK;

    // ---------------- hash encoding -> h0 block (64B rows, swizzled) ----------------
    {
        int p  = tid & 63;
        int lg = tid >> 6;                 // 0..7; handles levels lg, lg+8
        float2 cc = ((const float2*)coords)[pbase + p];
        #pragma unroll
        for (int li = 0; li < 2; ++li) {
            int l = lg + 8 * li;
            if (l < 10) {
                float R  = (float)res.r[l];
                float fx = cc.x * R, fy = cc.y * R;
                float x0 = floorf(fx), y0 = floorf(fy);
                float wx = fx - x0,  wy = fy - y0;
                unsigned xi = (unsigned)x0, yi = (unsigned)y0;
                unsigned yp  = yi * 2654435761u;
                unsigned yp1 = (yi + 1u) * 2654435761u;
                unsigned h00 = (xi        ^ yp ) & 4095u;
                unsigned h10 = ((xi + 1u) ^ yp ) & 4095u;
                unsigned h01 = (xi        ^ yp1) & 4095u;
                unsigned h11 = ((xi + 1u) ^ yp1) & 4095u;
                const float2* tl = (const float2*)(table + l * 8192);
                float2 f00 = tl[h00], f10 = tl[h10], f01 = tl[h01], f11 = tl[h11];
                float a0 = f00.x + (f10.x - f00.x) * wx;
                float a1 = f01.x + (f11.x - f01.x) * wx;
                float g0 = a0 + (a1 - a0) * wy;
                float c0 = f00.y + (f10.y - f00.y) * wx;
                float c1 = f01.y + (f11.y - f01.y) * wx;
                float g1 = c0 + (c1 - c0) * wy;
                unsigned pk = (unsigned)f2bf(g0) | ((unsigned)f2bf(g1) << 16);
                *(unsigned*)(sm + H0_OFF + (((p << 6) + 4*l) ^ ((p & 7) << 4))) = pk;
            }
        }
        if (lg == 2) {   // coords -> cols 20,21 (byte 40)
            unsigned pk = (unsigned)f2bf(cc.x) | ((unsigned)f2bf(cc.y) << 16);
            *(unsigned*)(sm + H0_OFF + (((p << 6) + 40) ^ ((p & 7) << 4))) = pk;
        }
        if (lg == 3) {   // zero pad cols 22..31 (bytes 44..63)
            #pragma unroll
            for (int bb = 44; bb < 64; bb += 4)
                *(unsigned*)(sm + H0_OFF + (((p << 6) + bb) ^ ((p & 7) << 4))) = 0u;
        }
    }
    __syncthreads();

    const int wid  = tid >> 6;
    const int lane = tid & 63;

    mlp_layer<0,  true,  false>(sm, Wp + OFF_W1,  b1,  wid, lane);  // h0 -> act
    mlp_layer<16, false, true >(sm, Wp + OFF_W2,  b2,  wid, lane);  // act -> act
    mlp_layer<16, true,  true >(sm, Wp + OFF_WS1, bs1, wid, lane);  // [act|h0] -> act
    mlp_layer<16, false, true >(sm, Wp + OFF_WS2, bs2, wid, lane);  // act -> act

    // ---------------- output layer: 512 -> 2, sin, f32 out ----------------
    {
        int p = tid >> 3, g = tid & 7;
        const unsigned short* wo0 = Wp + OFF_WO + g * 64;
        const unsigned short* wo1 = wo0 + 512;
        int xm = (p & 7) << 4;
        float s0 = 0.f, s1 = 0.f;
        #pragma unroll
        for (int kk = 0; kk < 8; ++kk) {
            int off = ((p << 10) + g*128 + kk*16) ^ xm;
            bf16x8 av  = *(const bf16x8*)(sm + off);
            bf16x8 w0  = *(const bf16x8*)(wo0 + kk * 8);
            bf16x8 w1v = *(const bf16x8*)(wo1 + kk * 8);
            #pragma unroll
            for (int j = 0; j < 8; ++j) {
                float a = bf2f((unsigned short)av[j]);
                s0 += a * bf2f((unsigned short)w0[j]);
                s1 += a * bf2f((unsigned short)w1v[j]);
            }
        }
        #pragma unroll
        for (int m = 1; m < 8; m <<= 1) {
            s0 += __shfl_xor(s0, m, 64);
            s1 += __shfl_xor(s1, m, 64);
        }
        if (g == 0) {
            float2 o;
            o.x = __sinf(s0 + bo[0]);
            o.y = __sinf(s1 + bo[1]);
            ((float2*)outp)[pbase + p] = o;
        }
    }
}

extern "C" void kernel_launch(void* const* d_in, const int* in_sizes, int n_in,
                              void* d_out, int out_size, void* d_ws, size_t ws_size,
                              hipStream_t stream)
{
    const float* coords = (const float*)d_in[0];
    const float* table  = (const float*)d_in[1];
    const float* w1  = (const float*)d_in[2];
    const float* b1  = (const float*)d_in[3];
    const float* w2  = (const float*)d_in[4];
    const float* b2  = (const float*)d_in[5];
    const float* ws1 = (const float*)d_in[6];
    const float* bs1 = (const float*)d_in[7];
    const float* ws2 = (const float*)d_in[8];
    const float* bs2 = (const float*)d_in[9];
    const float* wo  = (const float*)d_in[10];
    const float* bo  = (const float*)d_in[11];

    unsigned short* Wp = (unsigned short*)d_ws;
    float* outp = (float*)d_out;

    // RES computed with the exact double-precision op sequence of the reference
    ResArr res;
    double bb = exp((log(320.0) - log(16.0)) / 9.0);
    for (int l = 0; l < 10; ++l) res.r[l] = (int)floor(16.0 * pow(bb, (double)l));

    (void)hipFuncSetAttribute((const void*)siren_fused,
                              hipFuncAttributeMaxDynamicSharedMemorySize, LDSB);

    int N = in_sizes[0] / 2;      // 262144

    pack_weights<<<(NPACK + 255) / 256, 256, 0, stream>>>(w1, w2, ws1, ws2, wo, Wp);
    siren_fused<<<N / MBLK, 512, LDSB, stream>>>(coords, table, b1, b2, bs1, bs2, bo,
                                                 Wp, outp, res);
}

// Round 7
// 488.277 us; speedup vs baseline: 1.8236x; 1.3404x over previous
//
#include <hip/hip_runtime.h>
#include <hip/hip_bf16.h>
#include <math.h>

#define MBLK    64
#define H0_OFF  65536                 // act: 64 rows x 1024B (512 bf16), XOR-swizzled
#define LDSB    (H0_OFF + 64*64)      // +h0: 64 rows x 64B -> 69632 total (2 blocks/CU)

// packed bf16 weight offsets (ushort elements) inside d_ws
// layout per layer: [nb(8)][chunk(KC)][nf(4)][lane(64)][j(8)]  (coalesced per-wave loads)
#define OFF_W1  0
#define OFF_W2  16384                    // 8*1*4*512
#define OFF_WS1 (16384+262144)           // 278528
#define OFF_WS2 (278528+278528)          // 557056
#define OFF_WO  (557056+262144)          // 819200 (wo row-major, 1024)
#define NPACK   (819200+1024)            // 820224

typedef __attribute__((ext_vector_type(8))) short bf16x8;
typedef __attribute__((ext_vector_type(4))) float f32x4;

struct ResArr { int r[10]; };

__device__ __forceinline__ unsigned short f2bf(float f) {
    unsigned u = __float_as_uint(f);
    u += 0x7FFFu + ((u >> 16) & 1u);       // RNE — matches numpy; do NOT use v_cvt_pk_bf16_f32
    return (unsigned short)(u >> 16);
}
__device__ __forceinline__ float bf2f(unsigned short h) {
    return __uint_as_float(((unsigned)h) << 16);
}

__global__ void pack_weights(const float* __restrict__ w1, const float* __restrict__ w2,
                             const float* __restrict__ ws1, const float* __restrict__ ws2,
                             const float* __restrict__ wo, unsigned short* __restrict__ out)
{
    int i = blockIdx.x * 256 + threadIdx.x;
    if (i >= NPACK) return;
    float v;
    if (i < OFF_WO) {
        int il, KC, K_src, K_valid;
        const float* src;
        if (i < OFF_W2)       { il = i;           KC = 1;  K_src = 22;  K_valid = 22;  src = w1;  }
        else if (i < OFF_WS1) { il = i - OFF_W2;  KC = 16; K_src = 512; K_valid = 512; src = w2;  }
        else if (i < OFF_WS2) { il = i - OFF_WS1; KC = 17; K_src = 534; K_valid = 534; src = ws1; }
        else                  { il = i - OFF_WS2; KC = 16; K_src = 512; K_valid = 512; src = ws2; }
        int blk  = il >> 9, idx = il & 511;
        int lane = idx >> 3, j = idx & 7;
        int nf   = blk & 3;
        int rest = blk >> 2;
        int c    = rest % KC;
        int nb   = rest / KC;
        int n = nb * 64 + nf * 16 + (lane & 15);
        int k = c * 32 + (lane >> 4) * 8 + j;
        v = (k < K_valid) ? src[n * K_src + k] : 0.f;
    } else {
        v = wo[i - OFF_WO];
    }
    out[i] = f2bf(v);
}

// One MLP layer, in-place on the 64x512 act buffer.
// acc = mfma(act_frag, W_frag) => D: row=(lane>>4)*4+j -> act row offset, col=lane&15 -> n
template<int KSTEPS, bool TAIL, bool PREBAR>
__device__ __forceinline__ void mlp_layer(char* sm, const unsigned short* __restrict__ Wl,
                                          const float* __restrict__ bias,
                                          int wid, int lane)
{
    constexpr int NC = KSTEPS + (TAIL ? 1 : 0);
    const int n0 = wid * 64;
    const int lm = lane & 15;
    const int lk = lane >> 4;               // 0..3
    const int xm = (lm & 7) << 4;

    const unsigned short* wnb = Wl + (unsigned)(wid * NC) * 2048 + (lane << 3);

    float bv[4];
    #pragma unroll
    for (int nf = 0; nf < 4; ++nf) bv[nf] = bias[n0 + nf*16 + lm];

    f32x4 acc[4][4];
    #pragma unroll
    for (int i = 0; i < 4; ++i)
        #pragma unroll
        for (int j = 0; j < 4; ++j) { f32x4 z = {0.f,0.f,0.f,0.f}; acc[i][j] = z; }

    #pragma unroll 2
    for (int ks = 0; ks < KSTEPS; ++ks) {
        bf16x8 a[4], b[4];
        #pragma unroll
        for (int nf = 0; nf < 4; ++nf)
            b[nf] = *(const bf16x8*)(wnb + ((ks*4 + nf) << 9));
        #pragma unroll
        for (int mf = 0; mf < 4; ++mf)
            a[mf] = *(const bf16x8*)(sm + ((((mf*16 + lm) << 10) + ks*64 + lk*16) ^ xm));
        #pragma unroll
        for (int mf = 0; mf < 4; ++mf)
            #pragma unroll
            for (int nf = 0; nf < 4; ++nf)
                acc[mf][nf] = __builtin_amdgcn_mfma_f32_16x16x32_bf16(a[mf], b[nf], acc[mf][nf], 0, 0, 0);
    }
    if (TAIL) {   // K-tail of 32 from the h0 block (64B rows, swizzled)
        bf16x8 a[4], b[4];
        #pragma unroll
        for (int nf = 0; nf < 4; ++nf)
            b[nf] = *(const bf16x8*)(wnb + ((KSTEPS*4 + nf) << 9));
        #pragma unroll
        for (int mf = 0; mf < 4; ++mf)
            a[mf] = *(const bf16x8*)(sm + H0_OFF + ((((mf*16 + lm) << 6) + lk*16) ^ xm));
        #pragma unroll
        for (int mf = 0; mf < 4; ++mf)
            #pragma unroll
            for (int nf = 0; nf < 4; ++nf)
                acc[mf][nf] = __builtin_amdgcn_mfma_f32_16x16x32_bf16(a[mf], b[nf], acc[mf][nf], 0, 0, 0);
    }

    if (PREBAR) __syncthreads();    // all waves done reading act before overwrite

    // epilogue: bias + sin -> bf16 (manual RNE) -> act in-place
    #pragma unroll
    for (int nf = 0; nf < 4; ++nf) {
        const int colb = (n0 + nf*16 + lm) * 2;
        #pragma unroll
        for (int mf = 0; mf < 4; ++mf) {
            #pragma unroll
            for (int j = 0; j < 4; ++j) {
                int row = mf*16 + lk*4 + j;
                unsigned short h = f2bf(__sinf(acc[mf][nf][j] + bv[nf]));
                *(unsigned short*)(sm + (((row << 10) + colb) ^ ((row & 7) << 4))) = h;
            }
        }
    }
    __syncthreads();
}

__global__ __launch_bounds__(512) void siren_fused(
    const float* __restrict__ coords, const float* __restrict__ table,
    const float* __restrict__ b1, const float* __restrict__ b2,
    const float* __restrict__ bs1, const float* __restrict__ bs2,
    const float* __restrict__ bo,
    const unsigned short* __restrict__ Wp,
    float* __restrict__ outp,
    ResArr res)
{
    extern __shared__ char sm[];
    const int tid = threadIdx.x;
    const int pbase = blockIdx.x * MBLK;

    // ---------------- hash encoding -> h0 block (64B rows, swizzled) ----------------
    {
        int p  = tid & 63;
        int lg = tid >> 6;                 // 0..7; handles levels lg, lg+8
        float2 cc = ((const float2*)coords)[pbase + p];
        #pragma unroll
        for (int li = 0; li < 2; ++li) {
            int l = lg + 8 * li;
            if (l < 10) {
                float R  = (float)res.r[l];
                float fx = cc.x * R, fy = cc.y * R;
                float x0 = floorf(fx), y0 = floorf(fy);
                float wx = fx - x0,  wy = fy - y0;
                unsigned xi = (unsigned)x0, yi = (unsigned)y0;
                unsigned yp  = yi * 2654435761u;
                unsigned yp1 = (yi + 1u) * 2654435761u;
                unsigned h00 = (xi        ^ yp ) & 4095u;
                unsigned h10 = ((xi + 1u) ^ yp ) & 4095u;
                unsigned h01 = (xi        ^ yp1) & 4095u;
                unsigned h11 = ((xi + 1u) ^ yp1) & 4095u;
                const float2* tl = (const float2*)(table + l * 8192);
                float2 f00 = tl[h00], f10 = tl[h10], f01 = tl[h01], f11 = tl[h11];
                float a0 = f00.x + (f10.x - f00.x) * wx;
                float a1 = f01.x + (f11.x - f01.x) * wx;
                float g0 = a0 + (a1 - a0) * wy;
                float c0 = f00.y + (f10.y - f00.y) * wx;
                float c1 = f01.y + (f11.y - f01.y) * wx;
                float g1 = c0 + (c1 - c0) * wy;
                unsigned pk = (unsigned)f2bf(g0) | ((unsigned)f2bf(g1) << 16);
                *(unsigned*)(sm + H0_OFF + (((p << 6) + 4*l) ^ ((p & 7) << 4))) = pk;
            }
        }
        if (lg == 2) {   // coords -> cols 20,21 (byte 40)
            unsigned pk = (unsigned)f2bf(cc.x) | ((unsigned)f2bf(cc.y) << 16);
            *(unsigned*)(sm + H0_OFF + (((p << 6) + 40) ^ ((p & 7) << 4))) = pk;
        }
        if (lg == 3) {   // zero pad cols 22..31 (bytes 44..63)
            #pragma unroll
            for (int bb = 44; bb < 64; bb += 4)
                *(unsigned*)(sm + H0_OFF + (((p << 6) + bb) ^ ((p & 7) << 4))) = 0u;
        }
    }
    __syncthreads();

    const int wid  = tid >> 6;
    const int lane = tid & 63;

    mlp_layer<0,  true,  false>(sm, Wp + OFF_W1,  b1,  wid, lane);  // h0 -> act
    mlp_layer<16, false, true >(sm, Wp + OFF_W2,  b2,  wid, lane);  // act -> act
    mlp_layer<16, true,  true >(sm, Wp + OFF_WS1, bs1, wid, lane);  // [act|h0] -> act
    mlp_layer<16, false, true >(sm, Wp + OFF_WS2, bs2, wid, lane);  // act -> act

    // ---------------- output layer: 512 -> 2, sin, f32 out ----------------
    {
        int p = tid >> 3, g = tid & 7;
        const unsigned short* wo0 = Wp + OFF_WO + g * 64;
        const unsigned short* wo1 = wo0 + 512;
        int xm = (p & 7) << 4;
        float s0 = 0.f, s1 = 0.f;
        #pragma unroll
        for (int kk = 0; kk < 8; ++kk) {
            int off = ((p << 10) + g*128 + kk*16) ^ xm;
            bf16x8 av  = *(const bf16x8*)(sm + off);
            bf16x8 w0  = *(const bf16x8*)(wo0 + kk * 8);
            bf16x8 w1v = *(const bf16x8*)(wo1 + kk * 8);
            #pragma unroll
            for (int j = 0; j < 8; ++j) {
                float a = bf2f((unsigned short)av[j]);
                s0 += a * bf2f((unsigned short)w0[j]);
                s1 += a * bf2f((unsigned short)w1v[j]);
            }
        }
        #pragma unroll
        for (int m = 1; m < 8; m <<= 1) {
            s0 += __shfl_xor(s0, m, 64);
            s1 += __shfl_xor(s1, m, 64);
        }
        if (g == 0) {
            float2 o;
            o.x = __sinf(s0 + bo[0]);
            o.y = __sinf(s1 + bo[1]);
            ((float2*)outp)[pbase + p] = o;
        }
    }
}

extern "C" void kernel_launch(void* const* d_in, const int* in_sizes, int n_in,
                              void* d_out, int out_size, void* d_ws, size_t ws_size,
                              hipStream_t stream)
{
    const float* coords = (const float*)d_in[0];
    const float* table  = (const float*)d_in[1];
    const float* w1  = (const float*)d_in[2];
    const float* b1  = (const float*)d_in[3];
    const float* w2  = (const float*)d_in[4];
    const float* b2  = (const float*)d_in[5];
    const float* ws1 = (const float*)d_in[6];
    const float* bs1 = (const float*)d_in[7];
    const float* ws2 = (const float*)d_in[8];
    const float* bs2 = (const float*)d_in[9];
    const float* wo  = (const float*)d_in[10];
    const float* bo  = (const float*)d_in[11];

    unsigned short* Wp = (unsigned short*)d_ws;
    float* outp = (float*)d_out;

    // RES computed with the exact double-precision op sequence of the reference
    ResArr res;
    double bb = exp((log(320.0) - log(16.0)) / 9.0);
    for (int l = 0; l < 10; ++l) res.r[l] = (int)floor(16.0 * pow(bb, (double)l));

    (void)hipFuncSetAttribute((const void*)siren_fused,
                              hipFuncAttributeMaxDynamicSharedMemorySize, LDSB);

    int N = in_sizes[0] / 2;      // 262144

    pack_weights<<<(NPACK + 255) / 256, 256, 0, stream>>>(w1, w2, ws1, ws2, wo, Wp);
    siren_fused<<<N / MBLK, 512, LDSB, stream>>>(coords, table, b1, b2, bs1, bs2, bo,
                                                 Wp, outp, res);
}

// Round 8
// 476.854 us; speedup vs baseline: 1.8673x; 1.0240x over previous
//
#include <hip/hip_runtime.h>
#include <hip/hip_bf16.h>
#include <math.h>

#define MBLK    64
#define H0_OFF  65536                 // act: 64 rows x 1024B (512 bf16), XOR-swizzled
#define LDSB    (H0_OFF + 64*64)      // +h0: 64 rows x 64B -> 69632 total (2 blocks/CU)

// packed bf16 weight offsets (ushort elements) inside d_ws
// layout per layer: [nb(8)][chunk(KC)][nf(4)][lane(64)][j(8)]  (coalesced per-wave loads)
#define OFF_W1  0
#define OFF_W2  16384                    // 8*1*4*512
#define OFF_WS1 (16384+262144)           // 278528
#define OFF_WS2 (278528+278528)          // 557056
#define OFF_WO  (557056+262144)          // 819200 (wo row-major, 1024)
#define NPACK   (819200+1024)            // 820224

typedef __attribute__((ext_vector_type(8))) short bf16x8;
typedef __attribute__((ext_vector_type(4))) float f32x4;

struct ResArr { int r[10]; };

__device__ __forceinline__ unsigned short f2bf(float f) {
    unsigned u = __float_as_uint(f);
    u += 0x7FFFu + ((u >> 16) & 1u);       // RNE — matches numpy; do NOT use v_cvt_pk_bf16_f32
    return (unsigned short)(u >> 16);
}
__device__ __forceinline__ float bf2f(unsigned short h) {
    return __uint_as_float(((unsigned)h) << 16);
}

__global__ void pack_weights(const float* __restrict__ w1, const float* __restrict__ w2,
                             const float* __restrict__ ws1, const float* __restrict__ ws2,
                             const float* __restrict__ wo, unsigned short* __restrict__ out)
{
    int i = blockIdx.x * 256 + threadIdx.x;
    if (i >= NPACK) return;
    float v;
    if (i < OFF_WO) {
        int il, KC, K_src, K_valid;
        const float* src;
        if (i < OFF_W2)       { il = i;           KC = 1;  K_src = 22;  K_valid = 22;  src = w1;  }
        else if (i < OFF_WS1) { il = i - OFF_W2;  KC = 16; K_src = 512; K_valid = 512; src = w2;  }
        else if (i < OFF_WS2) { il = i - OFF_WS1; KC = 17; K_src = 534; K_valid = 534; src = ws1; }
        else                  { il = i - OFF_WS2; KC = 16; K_src = 512; K_valid = 512; src = ws2; }
        int blk  = il >> 9, idx = il & 511;
        int lane = idx >> 3, j = idx & 7;
        int nf   = blk & 3;
        int rest = blk >> 2;
        int c    = rest % KC;
        int nb   = rest / KC;
        int n = nb * 64 + nf * 16 + (lane & 15);
        int k = c * 32 + (lane >> 4) * 8 + j;
        v = (k < K_valid) ? src[n * K_src + k] : 0.f;
    } else {
        v = wo[i - OFF_WO];
    }
    out[i] = f2bf(v);
}

// One MLP layer, in-place on the 64x512 act buffer.
// acc = mfma(act_frag, W_frag) => D: row=(lane>>4)*4+j -> act row offset, col=lane&15 -> n
template<int KSTEPS, bool TAIL, bool PREBAR>
__device__ __forceinline__ void mlp_layer(char* sm, const unsigned short* __restrict__ Wl,
                                          const float* __restrict__ bias,
                                          int wid, int lane)
{
    constexpr int NC = KSTEPS + (TAIL ? 1 : 0);
    const int n0 = wid * 64;
    const int lm = lane & 15;
    const int lk = lane >> 4;               // 0..3
    const int xm = (lm & 7) << 4;

    const unsigned short* wnb = Wl + (unsigned)(wid * NC) * 2048 + (lane << 3);

    f32x4 acc[4][4];
    #pragma unroll
    for (int i = 0; i < 4; ++i)
        #pragma unroll
        for (int j = 0; j < 4; ++j) { f32x4 z = {0.f,0.f,0.f,0.f}; acc[i][j] = z; }

    #pragma unroll 1
    for (int ks = 0; ks < KSTEPS; ++ks) {
        bf16x8 a[4], b[4];
        #pragma unroll
        for (int nf = 0; nf < 4; ++nf)
            b[nf] = *(const bf16x8*)(wnb + ((ks*4 + nf) << 9));
        #pragma unroll
        for (int mf = 0; mf < 4; ++mf)
            a[mf] = *(const bf16x8*)(sm + ((((mf*16 + lm) << 10) + ks*64 + lk*16) ^ xm));
        #pragma unroll
        for (int mf = 0; mf < 4; ++mf)
            #pragma unroll
            for (int nf = 0; nf < 4; ++nf)
                acc[mf][nf] = __builtin_amdgcn_mfma_f32_16x16x32_bf16(a[mf], b[nf], acc[mf][nf], 0, 0, 0);
    }
    if (TAIL) {   // K-tail of 32 from the h0 block (64B rows, swizzled)
        bf16x8 a[4], b[4];
        #pragma unroll
        for (int nf = 0; nf < 4; ++nf)
            b[nf] = *(const bf16x8*)(wnb + ((KSTEPS*4 + nf) << 9));
        #pragma unroll
        for (int mf = 0; mf < 4; ++mf)
            a[mf] = *(const bf16x8*)(sm + H0_OFF + ((((mf*16 + lm) << 6) + lk*16) ^ xm));
        #pragma unroll
        for (int mf = 0; mf < 4; ++mf)
            #pragma unroll
            for (int nf = 0; nf < 4; ++nf)
                acc[mf][nf] = __builtin_amdgcn_mfma_f32_16x16x32_bf16(a[mf], b[nf], acc[mf][nf], 0, 0, 0);
    }

    if (PREBAR) __syncthreads();    // all waves done reading act before overwrite

    // epilogue: bias + sin -> bf16 (manual RNE) -> act in-place
    #pragma unroll
    for (int nf = 0; nf < 4; ++nf) {
        const float bv = bias[n0 + nf*16 + lm];
        const int colb = (n0 + nf*16 + lm) * 2;
        #pragma unroll
        for (int mf = 0; mf < 4; ++mf) {
            #pragma unroll
            for (int j = 0; j < 4; ++j) {
                int row = mf*16 + lk*4 + j;
                unsigned short h = f2bf(__sinf(acc[mf][nf][j] + bv));
                *(unsigned short*)(sm + (((row << 10) + colb) ^ ((row & 7) << 4))) = h;
            }
        }
    }
    __syncthreads();
}

__global__ __launch_bounds__(512, 2) void siren_fused(
    const float* __restrict__ coords, const float* __restrict__ table,
    const float* __restrict__ b1, const float* __restrict__ b2,
    const float* __restrict__ bs1, const float* __restrict__ bs2,
    const float* __restrict__ bo,
    const unsigned short* __restrict__ Wp,
    float* __restrict__ outp,
    ResArr res)
{
    extern __shared__ char sm[];
    const int tid = threadIdx.x;
    const int pbase = blockIdx.x * MBLK;

    // ---------------- hash encoding -> h0 block (64B rows, swizzled) ----------------
    {
        int p  = tid & 63;
        int lg = tid >> 6;                 // 0..7; handles levels lg, lg+8
        float2 cc = ((const float2*)coords)[pbase + p];
        #pragma unroll
        for (int li = 0; li < 2; ++li) {
            int l = lg + 8 * li;
            if (l < 10) {
                float R  = (float)res.r[l];
                float fx = cc.x * R, fy = cc.y * R;
                float x0 = floorf(fx), y0 = floorf(fy);
                float wx = fx - x0,  wy = fy - y0;
                unsigned xi = (unsigned)x0, yi = (unsigned)y0;
                unsigned yp  = yi * 2654435761u;
                unsigned yp1 = (yi + 1u) * 2654435761u;
                unsigned h00 = (xi        ^ yp ) & 4095u;
                unsigned h10 = ((xi + 1u) ^ yp ) & 4095u;
                unsigned h01 = (xi        ^ yp1) & 4095u;
                unsigned h11 = ((xi + 1u) ^ yp1) & 4095u;
                const float2* tl = (const float2*)(table + l * 8192);
                float2 f00 = tl[h00], f10 = tl[h10], f01 = tl[h01], f11 = tl[h11];
                float a0 = f00.x + (f10.x - f00.x) * wx;
                float a1 = f01.x + (f11.x - f01.x) * wx;
                float g0 = a0 + (a1 - a0) * wy;
                float c0 = f00.y + (f10.y - f00.y) * wx;
                float c1 = f01.y + (f11.y - f01.y) * wx;
                float g1 = c0 + (c1 - c0) * wy;
                unsigned pk = (unsigned)f2bf(g0) | ((unsigned)f2bf(g1) << 16);
                *(unsigned*)(sm + H0_OFF + (((p << 6) + 4*l) ^ ((p & 7) << 4))) = pk;
            }
        }
        if (lg == 2) {   // coords -> cols 20,21 (byte 40)
            unsigned pk = (unsigned)f2bf(cc.x) | ((unsigned)f2bf(cc.y) << 16);
            *(unsigned*)(sm + H0_OFF + (((p << 6) + 40) ^ ((p & 7) << 4))) = pk;
        }
        if (lg == 3) {   // zero pad cols 22..31 (bytes 44..63)
            #pragma unroll
            for (int bb = 44; bb < 64; bb += 4)
                *(unsigned*)(sm + H0_OFF + (((p << 6) + bb) ^ ((p & 7) << 4))) = 0u;
        }
    }
    __syncthreads();

    const int wid  = tid >> 6;
    const int lane = tid & 63;

    mlp_layer<0,  true,  false>(sm, Wp + OFF_W1,  b1,  wid, lane);  // h0 -> act
    mlp_layer<16, false, true >(sm, Wp + OFF_W2,  b2,  wid, lane);  // act -> act
    mlp_layer<16, true,  true >(sm, Wp + OFF_WS1, bs1, wid, lane);  // [act|h0] -> act
    mlp_layer<16, false, true >(sm, Wp + OFF_WS2, bs2, wid, lane);  // act -> act

    // ---------------- output layer: 512 -> 2, sin, f32 out ----------------
    {
        int p = tid >> 3, g = tid & 7;
        const unsigned short* wo0 = Wp + OFF_WO + g * 64;
        const unsigned short* wo1 = wo0 + 512;
        int xm = (p & 7) << 4;
        float s0 = 0.f, s1 = 0.f;
        #pragma unroll
        for (int kk = 0; kk < 8; ++kk) {
            int off = ((p << 10) + g*128 + kk*16) ^ xm;
            bf16x8 av  = *(const bf16x8*)(sm + off);
            bf16x8 w0  = *(const bf16x8*)(wo0 + kk * 8);
            bf16x8 w1v = *(const bf16x8*)(wo1 + kk * 8);
            #pragma unroll
            for (int j = 0; j < 8; ++j) {
                float a = bf2f((unsigned short)av[j]);
                s0 += a * bf2f((unsigned short)w0[j]);
                s1 += a * bf2f((unsigned short)w1v[j]);
            }
        }
        #pragma unroll
        for (int m = 1; m < 8; m <<= 1) {
            s0 += __shfl_xor(s0, m, 64);
            s1 += __shfl_xor(s1, m, 64);
        }
        if (g == 0) {
            float2 o;
            o.x = __sinf(s0 + bo[0]);
            o.y = __sinf(s1 + bo[1]);
            ((float2*)outp)[pbase + p] = o;
        }
    }
}

extern "C" void kernel_launch(void* const* d_in, const int* in_sizes, int n_in,
                              void* d_out, int out_size, void* d_ws, size_t ws_size,
                              hipStream_t stream)
{
    const float* coords = (const float*)d_in[0];
    const float* table  = (const float*)d_in[1];
    const float* w1  = (const float*)d_in[2];
    const float* b1  = (const float*)d_in[3];
    const float* w2  = (const float*)d_in[4];
    const float* b2  = (const float*)d_in[5];
    const float* ws1 = (const float*)d_in[6];
    const float* bs1 = (const float*)d_in[7];
    const float* ws2 = (const float*)d_in[8];
    const float* bs2 = (const float*)d_in[9];
    const float* wo  = (const float*)d_in[10];
    const float* bo  = (const float*)d_in[11];

    unsigned short* Wp = (unsigned short*)d_ws;
    float* outp = (float*)d_out;

    // RES computed with the exact double-precision op sequence of the reference
    ResArr res;
    double bb = exp((log(320.0) - log(16.0)) / 9.0);
    for (int l = 0; l < 10; ++l) res.r[l] = (int)floor(16.0 * pow(bb, (double)l));

    (void)hipFuncSetAttribute((const void*)siren_fused,
                              hipFuncAttributeMaxDynamicSharedMemorySize, LDSB);

    int N = in_sizes[0] / 2;      // 262144

    pack_weights<<<(NPACK + 255) / 256, 256, 0, stream>>>(w1, w2, ws1, ws2, wo, Wp);
    siren_fused<<<N / MBLK, 512, LDSB, stream>>>(coords, table, b1, b2, bs1, bs2, bo,
                                                 Wp, outp, res);
}

// Round 9
// 444.846 us; speedup vs baseline: 2.0017x; 1.0720x over previous
//
#include <hip/hip_runtime.h>
#include <hip/hip_bf16.h>
#include <math.h>

#define MBLK    64
#define H0_OFF  65536                 // act: 64 rows x 1024B (512 bf16), XOR-swizzled
#define LDSB    (H0_OFF + 64*64)      // +h0: 64 rows x 64B -> 69632

// packed bf16 weight offsets (ushort elements) inside d_ws
// layout per layer: [nb(16)][chunk(KC)][nf(2)][lane(64)][j(8)]  (coalesced per-wave loads)
#define OFF_W1  0
#define OFF_W2  16384                    // 16*1*2*512
#define OFF_WS1 (16384+262144)           // 278528
#define OFF_WS2 (278528+278528)          // 557056
#define OFF_WO  (557056+262144)          // 819200 (wo row-major, 1024)
#define NPACK   (819200+1024)            // 820224

typedef __attribute__((ext_vector_type(8))) short bf16x8;
typedef __attribute__((ext_vector_type(4))) float f32x4;

struct ResArr { int r[10]; };

__device__ __forceinline__ unsigned short f2bf(float f) {
    unsigned u = __float_as_uint(f);
    u += 0x7FFFu + ((u >> 16) & 1u);       // RNE — matches numpy; do NOT use v_cvt_pk_bf16_f32
    return (unsigned short)(u >> 16);
}
__device__ __forceinline__ float bf2f(unsigned short h) {
    return __uint_as_float(((unsigned)h) << 16);
}

__global__ void pack_weights(const float* __restrict__ w1, const float* __restrict__ w2,
                             const float* __restrict__ ws1, const float* __restrict__ ws2,
                             const float* __restrict__ wo, unsigned short* __restrict__ out)
{
    int i = blockIdx.x * 256 + threadIdx.x;
    if (i >= NPACK) return;
    float v;
    if (i < OFF_WO) {
        int il, KC, K_src, K_valid;
        const float* src;
        if (i < OFF_W2)       { il = i;           KC = 1;  K_src = 22;  K_valid = 22;  src = w1;  }
        else if (i < OFF_WS1) { il = i - OFF_W2;  KC = 16; K_src = 512; K_valid = 512; src = w2;  }
        else if (i < OFF_WS2) { il = i - OFF_WS1; KC = 17; K_src = 534; K_valid = 534; src = ws1; }
        else                  { il = i - OFF_WS2; KC = 16; K_src = 512; K_valid = 512; src = ws2; }
        int blk  = il >> 9, idx = il & 511;
        int lane = idx >> 3, j = idx & 7;
        int nf   = blk & 1;
        int rest = blk >> 1;
        int c    = rest % KC;
        int nb   = rest / KC;
        int n = nb * 32 + nf * 16 + (lane & 15);
        int k = c * 32 + (lane >> 4) * 8 + j;
        v = (k < K_valid) ? src[n * K_src + k] : 0.f;
    } else {
        v = wo[i - OFF_WO];
    }
    out[i] = f2bf(v);
}

// One MLP layer, in-place on the 64x512 act buffer. 16 waves; each owns 64 rows x 32 cols.
// acc = mfma(act_frag, W_frag) => D: row=(lane>>4)*4+j -> act row offset, col=lane&15 -> n
template<int KSTEPS, bool TAIL, bool PREBAR>
__device__ __forceinline__ void mlp_layer(char* sm, const unsigned short* __restrict__ Wl,
                                          const float* __restrict__ bias,
                                          int wid, int lane)
{
    constexpr int NC = KSTEPS + (TAIL ? 1 : 0);
    const int n0 = wid * 32;
    const int lm = lane & 15;
    const int lk = lane >> 4;               // 0..3
    const int xm = (lm & 7) << 4;

    const unsigned short* wnb = Wl + (unsigned)(wid * NC) * 1024 + (lane << 3);

    f32x4 acc[4][2];
    #pragma unroll
    for (int i = 0; i < 4; ++i)
        #pragma unroll
        for (int j = 0; j < 2; ++j) { f32x4 z = {0.f,0.f,0.f,0.f}; acc[i][j] = z; }

    #pragma unroll 1
    for (int ks = 0; ks < KSTEPS; ++ks) {
        bf16x8 a[4], b[2];
        #pragma unroll
        for (int nf = 0; nf < 2; ++nf)
            b[nf] = *(const bf16x8*)(wnb + ((ks*2 + nf) << 9));
        #pragma unroll
        for (int mf = 0; mf < 4; ++mf)
            a[mf] = *(const bf16x8*)(sm + ((((mf*16 + lm) << 10) + ks*64 + lk*16) ^ xm));
        #pragma unroll
        for (int mf = 0; mf < 4; ++mf)
            #pragma unroll
            for (int nf = 0; nf < 2; ++nf)
                acc[mf][nf] = __builtin_amdgcn_mfma_f32_16x16x32_bf16(a[mf], b[nf], acc[mf][nf], 0, 0, 0);
    }
    if (TAIL) {   // K-tail of 32 from the h0 block (64B rows, swizzled)
        bf16x8 a[4], b[2];
        #pragma unroll
        for (int nf = 0; nf < 2; ++nf)
            b[nf] = *(const bf16x8*)(wnb + ((KSTEPS*2 + nf) << 9));
        #pragma unroll
        for (int mf = 0; mf < 4; ++mf)
            a[mf] = *(const bf16x8*)(sm + H0_OFF + ((((mf*16 + lm) << 6) + lk*16) ^ xm));
        #pragma unroll
        for (int mf = 0; mf < 4; ++mf)
            #pragma unroll
            for (int nf = 0; nf < 2; ++nf)
                acc[mf][nf] = __builtin_amdgcn_mfma_f32_16x16x32_bf16(a[mf], b[nf], acc[mf][nf], 0, 0, 0);
    }

    if (PREBAR) __syncthreads();    // all waves done reading act before overwrite

    // epilogue: bias + sin -> bf16 (manual RNE) -> act in-place
    #pragma unroll
    for (int nf = 0; nf < 2; ++nf) {
        const float bv = bias[n0 + nf*16 + lm];
        const int colb = (n0 + nf*16 + lm) * 2;
        #pragma unroll
        for (int mf = 0; mf < 4; ++mf) {
            #pragma unroll
            for (int j = 0; j < 4; ++j) {
                int row = mf*16 + lk*4 + j;
                unsigned short h = f2bf(__sinf(acc[mf][nf][j] + bv));
                *(unsigned short*)(sm + (((row << 10) + colb) ^ ((row & 7) << 4))) = h;
            }
        }
    }
    __syncthreads();
}

__global__ __launch_bounds__(1024) void siren_fused(
    const float* __restrict__ coords, const float* __restrict__ table,
    const float* __restrict__ b1, const float* __restrict__ b2,
    const float* __restrict__ bs1, const float* __restrict__ bs2,
    const float* __restrict__ bo,
    const unsigned short* __restrict__ Wp,
    float* __restrict__ outp,
    ResArr res)
{
    extern __shared__ char sm[];
    const int tid = threadIdx.x;
    const int pbase = blockIdx.x * MBLK;

    // ---------------- hash encoding -> h0 block (64B rows, swizzled) ----------------
    {
        int p  = tid & 63;
        int lg = tid >> 6;                 // 0..15; lg<10: level lg, lg==10: coords, lg==11: pad
        float2 cc = ((const float2*)coords)[pbase + p];
        if (lg < 10) {
            float R  = (float)res.r[lg];
            float fx = cc.x * R, fy = cc.y * R;
            float x0 = floorf(fx), y0 = floorf(fy);
            float wx = fx - x0,  wy = fy - y0;
            unsigned xi = (unsigned)x0, yi = (unsigned)y0;
            unsigned yp  = yi * 2654435761u;
            unsigned yp1 = (yi + 1u) * 2654435761u;
            unsigned h00 = (xi        ^ yp ) & 4095u;
            unsigned h10 = ((xi + 1u) ^ yp ) & 4095u;
            unsigned h01 = (xi        ^ yp1) & 4095u;
            unsigned h11 = ((xi + 1u) ^ yp1) & 4095u;
            const float2* tl = (const float2*)(table + lg * 8192);
            float2 f00 = tl[h00], f10 = tl[h10], f01 = tl[h01], f11 = tl[h11];
            float a0 = f00.x + (f10.x - f00.x) * wx;
            float a1 = f01.x + (f11.x - f01.x) * wx;
            float g0 = a0 + (a1 - a0) * wy;
            float c0 = f00.y + (f10.y - f00.y) * wx;
            float c1 = f01.y + (f11.y - f01.y) * wx;
            float g1 = c0 + (c1 - c0) * wy;
            unsigned pk = (unsigned)f2bf(g0) | ((unsigned)f2bf(g1) << 16);
            *(unsigned*)(sm + H0_OFF + (((p << 6) + 4*lg) ^ ((p & 7) << 4))) = pk;
        } else if (lg == 10) {   // coords -> cols 20,21 (byte 40)
            unsigned pk = (unsigned)f2bf(cc.x) | ((unsigned)f2bf(cc.y) << 16);
            *(unsigned*)(sm + H0_OFF + (((p << 6) + 40) ^ ((p & 7) << 4))) = pk;
        } else if (lg == 11) {   // zero pad cols 22..31 (bytes 44..63)
            #pragma unroll
            for (int bb = 44; bb < 64; bb += 4)
                *(unsigned*)(sm + H0_OFF + (((p << 6) + bb) ^ ((p & 7) << 4))) = 0u;
        }
    }
    __syncthreads();

    const int wid  = tid >> 6;
    const int lane = tid & 63;

    mlp_layer<0,  true,  false>(sm, Wp + OFF_W1,  b1,  wid, lane);  // h0 -> act
    mlp_layer<16, false, true >(sm, Wp + OFF_W2,  b2,  wid, lane);  // act -> act
    mlp_layer<16, true,  true >(sm, Wp + OFF_WS1, bs1, wid, lane);  // [act|h0] -> act
    mlp_layer<16, false, true >(sm, Wp + OFF_WS2, bs2, wid, lane);  // act -> act

    // ---------------- output layer: 512 -> 2, sin, f32 out ----------------
    {
        int p = tid >> 4, g = tid & 15;    // p: point 0..63, g: k-group (32 cols each)
        const unsigned short* wo0 = Wp + OFF_WO + g * 32;
        const unsigned short* wo1 = wo0 + 512;
        int xm = (p & 7) << 4;
        float s0 = 0.f, s1 = 0.f;
        #pragma unroll
        for (int kk = 0; kk < 4; ++kk) {
            int off = ((p << 10) + g*64 + kk*16) ^ xm;
            bf16x8 av  = *(const bf16x8*)(sm + off);
            bf16x8 w0  = *(const bf16x8*)(wo0 + kk * 8);
            bf16x8 w1v = *(const bf16x8*)(wo1 + kk * 8);
            #pragma unroll
            for (int j = 0; j < 8; ++j) {
                float a = bf2f((unsigned short)av[j]);
                s0 += a * bf2f((unsigned short)w0[j]);
                s1 += a * bf2f((unsigned short)w1v[j]);
            }
        }
        #pragma unroll
        for (int m = 1; m < 16; m <<= 1) {
            s0 += __shfl_xor(s0, m, 64);
            s1 += __shfl_xor(s1, m, 64);
        }
        if (g == 0) {
            float2 o;
            o.x = __sinf(s0 + bo[0]);
            o.y = __sinf(s1 + bo[1]);
            ((float2*)outp)[pbase + p] = o;
        }
    }
}

extern "C" void kernel_launch(void* const* d_in, const int* in_sizes, int n_in,
                              void* d_out, int out_size, void* d_ws, size_t ws_size,
                              hipStream_t stream)
{
    const float* coords = (const float*)d_in[0];
    const float* table  = (const float*)d_in[1];
    const float* w1  = (const float*)d_in[2];
    const float* b1  = (const float*)d_in[3];
    const float* w2  = (const float*)d_in[4];
    const float* b2  = (const float*)d_in[5];
    const float* ws1 = (const float*)d_in[6];
    const float* bs1 = (const float*)d_in[7];
    const float* ws2 = (const float*)d_in[8];
    const float* bs2 = (const float*)d_in[9];
    const float* wo  = (const float*)d_in[10];
    const float* bo  = (const float*)d_in[11];

    unsigned short* Wp = (unsigned short*)d_ws;
    float* outp = (float*)d_out;

    // RES computed with the exact double-precision op sequence of the reference
    ResArr res;
    double bb = exp((log(320.0) - log(16.0)) / 9.0);
    for (int l = 0; l < 10; ++l) res.r[l] = (int)floor(16.0 * pow(bb, (double)l));

    (void)hipFuncSetAttribute((const void*)siren_fused,
                              hipFuncAttributeMaxDynamicSharedMemorySize, LDSB);

    int N = in_sizes[0] / 2;      // 262144

    pack_weights<<<(NPACK + 255) / 256, 256, 0, stream>>>(w1, w2, ws1, ws2, wo, Wp);
    siren_fused<<<N / MBLK, 1024, LDSB, stream>>>(coords, table, b1, b2, bs1, bs2, bo,
                                                  Wp, outp, res);
}

// Round 10
// 414.276 us; speedup vs baseline: 2.1494x; 1.0738x over previous
//
#include <hip/hip_runtime.h>
#include <hip/hip_bf16.h>
#include <math.h>

#define MBLK    64
#define H0_OFF  65536                 // act: 64 rows x 1024B (512 bf16), XOR-swizzled (row&15)<<4
#define LDSB    (H0_OFF + 64*64)      // +h0: 64 rows x 64B -> 69632 (2 blocks/CU)

// packed bf16 weight offsets (ushort elements) inside d_ws
// layout per layer: [nb(8)][chunk(KC)][nf(4)][lane(64)][j(8)]  (coalesced per-wave loads)
#define OFF_W1  0
#define OFF_W2  16384                    // 8*1*4*512
#define OFF_WS1 (16384+262144)           // 278528
#define OFF_WS2 (278528+278528)          // 557056
#define OFF_WO  (557056+262144)          // 819200 (wo row-major, 1024)
#define NPACK   (819200+1024)            // 820224

typedef __attribute__((ext_vector_type(8))) short bf16x8;
typedef __attribute__((ext_vector_type(4))) float f32x4;

struct ResArr { int r[10]; };

__device__ __forceinline__ unsigned short f2bf(float f) {
    unsigned u = __float_as_uint(f);
    u += 0x7FFFu + ((u >> 16) & 1u);       // RNE — matches numpy; do NOT use v_cvt_pk_bf16_f32
    return (unsigned short)(u >> 16);
}
__device__ __forceinline__ float bf2f(unsigned short h) {
    return __uint_as_float(((unsigned)h) << 16);
}

__global__ void pack_weights(const float* __restrict__ w1, const float* __restrict__ w2,
                             const float* __restrict__ ws1, const float* __restrict__ ws2,
                             const float* __restrict__ wo, unsigned short* __restrict__ out)
{
    int i = blockIdx.x * 256 + threadIdx.x;
    if (i >= NPACK) return;
    float v;
    if (i < OFF_WO) {
        int il, KC, K_src, K_valid;
        const float* src;
        if (i < OFF_W2)       { il = i;           KC = 1;  K_src = 22;  K_valid = 22;  src = w1;  }
        else if (i < OFF_WS1) { il = i - OFF_W2;  KC = 16; K_src = 512; K_valid = 512; src = w2;  }
        else if (i < OFF_WS2) { il = i - OFF_WS1; KC = 17; K_src = 534; K_valid = 534; src = ws1; }
        else                  { il = i - OFF_WS2; KC = 16; K_src = 512; K_valid = 512; src = ws2; }
        int blk  = il >> 9, idx = il & 511;
        int lane = idx >> 3, j = idx & 7;
        int nf   = blk & 3;
        int rest = blk >> 2;
        int c    = rest % KC;
        int nb   = rest / KC;
        int n = nb * 64 + nf * 16 + (lane & 15);
        int k = c * 32 + (lane >> 4) * 8 + j;
        v = (k < K_valid) ? src[n * K_src + k] : 0.f;
    } else {
        v = wo[i - OFF_WO];
    }
    out[i] = f2bf(v);
}

// One MLP layer, in-place on the 64x512 act buffer. 8 waves; wave owns 64 rows x 64 cols.
// SWAPPED operands: acc = mfma(W_frag, act_frag) => D: row(lk*4+j)=n-local, col(lane&15)=act row
template<int KSTEPS, bool TAIL, bool PREBAR>
__device__ __forceinline__ void mlp_layer(char* sm, const unsigned short* __restrict__ Wl,
                                          const float* __restrict__ bias,
                                          int wid, int lane)
{
    constexpr int NC = KSTEPS + (TAIL ? 1 : 0);
    const int n0 = wid * 64;
    const int lm = lane & 15;
    const int lk = lane >> 4;               // 0..3
    const int xm = lm << 4;                 // act swizzle: (row&15)<<4, row=mf*16+lm -> lm<<4

    const unsigned short* wnb = Wl + (unsigned)(wid * NC) * 2048 + (lane << 3);

    f32x4 acc[4][4];
    #pragma unroll
    for (int i = 0; i < 4; ++i)
        #pragma unroll
        for (int j = 0; j < 4; ++j) { f32x4 z = {0.f,0.f,0.f,0.f}; acc[i][j] = z; }

    #pragma unroll 1
    for (int ks = 0; ks < KSTEPS; ++ks) {
        bf16x8 w[4], a[4];
        #pragma unroll
        for (int nf = 0; nf < 4; ++nf)
            w[nf] = *(const bf16x8*)(wnb + ((ks*4 + nf) << 9));
        #pragma unroll
        for (int mf = 0; mf < 4; ++mf)
            a[mf] = *(const bf16x8*)(sm + ((((mf*16 + lm) << 10) + ks*64 + lk*16) ^ xm));
        #pragma unroll
        for (int mf = 0; mf < 4; ++mf)
            #pragma unroll
            for (int nf = 0; nf < 4; ++nf)
                acc[mf][nf] = __builtin_amdgcn_mfma_f32_16x16x32_bf16(w[nf], a[mf], acc[mf][nf], 0, 0, 0);
    }
    if (TAIL) {   // K-tail of 32 from the h0 block (64B rows, (row&7)<<4 swizzle)
        bf16x8 w[4], a[4];
        #pragma unroll
        for (int nf = 0; nf < 4; ++nf)
            w[nf] = *(const bf16x8*)(wnb + ((KSTEPS*4 + nf) << 9));
        #pragma unroll
        for (int mf = 0; mf < 4; ++mf)
            a[mf] = *(const bf16x8*)(sm + H0_OFF + ((((mf*16 + lm) << 6) + lk*16) ^ ((lm & 7) << 4)));
        #pragma unroll
        for (int mf = 0; mf < 4; ++mf)
            #pragma unroll
            for (int nf = 0; nf < 4; ++nf)
                acc[mf][nf] = __builtin_amdgcn_mfma_f32_16x16x32_bf16(w[nf], a[mf], acc[mf][nf], 0, 0, 0);
    }

    if (PREBAR) __syncthreads();    // all waves done reading act before overwrite

    // epilogue: lane's act row m = mf*16+lm; n = n0+nf*16+lk*4+{0..3} -> one uint2 per (mf,nf)
    #pragma unroll
    for (int nf = 0; nf < 4; ++nf) {
        const float4 bv = *(const float4*)(bias + n0 + nf*16 + lk*4);
        const int colb = (n0 + nf*16 + lk*4) * 2;
        #pragma unroll
        for (int mf = 0; mf < 4; ++mf) {
            float s0 = __sinf(acc[mf][nf][0] + bv.x);
            float s1 = __sinf(acc[mf][nf][1] + bv.y);
            float s2 = __sinf(acc[mf][nf][2] + bv.z);
            float s3 = __sinf(acc[mf][nf][3] + bv.w);
            uint2 pk;
            pk.x = (unsigned)f2bf(s0) | ((unsigned)f2bf(s1) << 16);
            pk.y = (unsigned)f2bf(s2) | ((unsigned)f2bf(s3) << 16);
            int row = mf*16 + lm;
            *(uint2*)(sm + (((row << 10) + colb) ^ xm)) = pk;
        }
    }
    __syncthreads();
}

__global__ __launch_bounds__(512) __attribute__((amdgpu_waves_per_eu(4))) void siren_fused(
    const float* __restrict__ coords, const float* __restrict__ table,
    const float* __restrict__ b1, const float* __restrict__ b2,
    const float* __restrict__ bs1, const float* __restrict__ bs2,
    const float* __restrict__ bo,
    const unsigned short* __restrict__ Wp,
    float* __restrict__ outp,
    ResArr res)
{
    extern __shared__ char sm[];
    const int tid = threadIdx.x;
    const int pbase = blockIdx.x * MBLK;

    // ---------------- hash encoding -> h0 block (64B rows, (p&7)<<4 swizzle) ----------------
    {
        int p  = tid & 63;
        int lg = tid >> 6;                 // 0..7; handles levels lg, lg+8
        float2 cc = ((const float2*)coords)[pbase + p];
        #pragma unroll
        for (int li = 0; li < 2; ++li) {
            int l = lg + 8 * li;
            if (l < 10) {
                float R  = (float)res.r[l];
                float fx = cc.x * R, fy = cc.y * R;
                float x0 = floorf(fx), y0 = floorf(fy);
                float wx = fx - x0,  wy = fy - y0;
                unsigned xi = (unsigned)x0, yi = (unsigned)y0;
                unsigned yp  = yi * 2654435761u;
                unsigned yp1 = (yi + 1u) * 2654435761u;
                unsigned h00 = (xi        ^ yp ) & 4095u;
                unsigned h10 = ((xi + 1u) ^ yp ) & 4095u;
                unsigned h01 = (xi        ^ yp1) & 4095u;
                unsigned h11 = ((xi + 1u) ^ yp1) & 4095u;
                const float2* tl = (const float2*)(table + l * 8192);
                float2 f00 = tl[h00], f10 = tl[h10], f01 = tl[h01], f11 = tl[h11];
                float a0 = f00.x + (f10.x - f00.x) * wx;
                float a1 = f01.x + (f11.x - f01.x) * wx;
                float g0 = a0 + (a1 - a0) * wy;
                float c0 = f00.y + (f10.y - f00.y) * wx;
                float c1 = f01.y + (f11.y - f01.y) * wx;
                float g1 = c0 + (c1 - c0) * wy;
                unsigned pk = (unsigned)f2bf(g0) | ((unsigned)f2bf(g1) << 16);
                *(unsigned*)(sm + H0_OFF + (((p << 6) + 4*l) ^ ((p & 7) << 4))) = pk;
            }
        }
        if (lg == 2) {   // coords -> cols 20,21 (byte 40)
            unsigned pk = (unsigned)f2bf(cc.x) | ((unsigned)f2bf(cc.y) << 16);
            *(unsigned*)(sm + H0_OFF + (((p << 6) + 40) ^ ((p & 7) << 4))) = pk;
        }
        if (lg == 3) {   // zero pad cols 22..31 (bytes 44..63)
            #pragma unroll
            for (int bb = 44; bb < 64; bb += 4)
                *(unsigned*)(sm + H0_OFF + (((p << 6) + bb) ^ ((p & 7) << 4))) = 0u;
        }
    }
    __syncthreads();

    const int wid  = tid >> 6;
    const int lane = tid & 63;

    mlp_layer<0,  true,  false>(sm, Wp + OFF_W1,  b1,  wid, lane);  // h0 -> act
    mlp_layer<16, false, true >(sm, Wp + OFF_W2,  b2,  wid, lane);  // act -> act
    mlp_layer<16, true,  true >(sm, Wp + OFF_WS1, bs1, wid, lane);  // [act|h0] -> act
    mlp_layer<16, false, true >(sm, Wp + OFF_WS2, bs2, wid, lane);  // act -> act

    // ---------------- output layer: 512 -> 2, sin, f32 out ----------------
    {
        int p = tid >> 3, g = tid & 7;
        const unsigned short* wo0 = Wp + OFF_WO + g * 64;
        const unsigned short* wo1 = wo0 + 512;
        int xm = (p & 15) << 4;
        float s0 = 0.f, s1 = 0.f;
        #pragma unroll
        for (int kk = 0; kk < 8; ++kk) {
            int off = ((p << 10) + g*128 + kk*16) ^ xm;
            bf16x8 av  = *(const bf16x8*)(sm + off);
            bf16x8 w0  = *(const bf16x8*)(wo0 + kk * 8);
            bf16x8 w1v = *(const bf16x8*)(wo1 + kk * 8);
            #pragma unroll
            for (int j = 0; j < 8; ++j) {
                float a = bf2f((unsigned short)av[j]);
                s0 += a * bf2f((unsigned short)w0[j]);
                s1 += a * bf2f((unsigned short)w1v[j]);
            }
        }
        #pragma unroll
        for (int m = 1; m < 8; m <<= 1) {
            s0 += __shfl_xor(s0, m, 64);
            s1 += __shfl_xor(s1, m, 64);
        }
        if (g == 0) {
            float2 o;
            o.x = __sinf(s0 + bo[0]);
            o.y = __sinf(s1 + bo[1]);
            ((float2*)outp)[pbase + p] = o;
        }
    }
}

extern "C" void kernel_launch(void* const* d_in, const int* in_sizes, int n_in,
                              void* d_out, int out_size, void* d_ws, size_t ws_size,
                              hipStream_t stream)
{
    const float* coords = (const float*)d_in[0];
    const float* table  = (const float*)d_in[1];
    const float* w1  = (const float*)d_in[2];
    const float* b1  = (const float*)d_in[3];
    const float* w2  = (const float*)d_in[4];
    const float* b2  = (const float*)d_in[5];
    const float* ws1 = (const float*)d_in[6];
    const float* bs1 = (const float*)d_in[7];
    const float* ws2 = (const float*)d_in[8];
    const float* bs2 = (const float*)d_in[9];
    const float* wo  = (const float*)d_in[10];
    const float* bo  = (const float*)d_in[11];

    unsigned short* Wp = (unsigned short*)d_ws;
    float* outp = (float*)d_out;

    // RES computed with the exact double-precision op sequence of the reference
    ResArr res;
    double bb = exp((log(320.0) - log(16.0)) / 9.0);
    for (int l = 0; l < 10; ++l) res.r[l] = (int)floor(16.0 * pow(bb, (double)l));

    (void)hipFuncSetAttribute((const void*)siren_fused,
                              hipFuncAttributeMaxDynamicSharedMemorySize, LDSB);

    int N = in_sizes[0] / 2;      // 262144

    pack_weights<<<(NPACK + 255) / 256, 256, 0, stream>>>(w1, w2, ws1, ws2, wo, Wp);
    siren_fused<<<N / MBLK, 512, LDSB, stream>>>(coords, table, b1, b2, bs1, bs2, bo,
                                                 Wp, outp, res);
}